// Round 1
// baseline (2361.700 us; speedup 1.0000x reference)
//
#include <hip/hip_runtime.h>

#define NN 100000
#define NE 1250000

// ---------------- workspace layout (in floats) ----------------
// cnt  @ 0          : NN floats (padded to 102400)
// h    @ 102400     : NN*128
// agg1 @ 12902400   : NN*64   (dead after gemm1)
// pq   @ 12902400   : NN*128  (overlaps agg1 -- fine, agg1 is dead)
// total = 25,702,400 floats = 102.8 MB
static constexpr size_t OFF_CNT = 0;
static constexpr size_t OFF_H   = 102400;
static constexpr size_t OFF_AGG = 12902400;
static constexpr size_t OFF_PQ  = 12902400;

// ---------------- scatter-add (+ optional degree count) ----------------
// 16 threads per edge, one float4 each (64 floats/edge).
__global__ __launch_bounds__(256) void sage_scatter(
    const int* __restrict__ srcv, const int* __restrict__ dstv,
    const float* __restrict__ feat, int fstride,
    float* __restrict__ acc, float* __restrict__ cnt)
{
    int t = blockIdx.x * 256 + threadIdx.x;   // NE*16 = 20M, fits int
    if (t >= NE * 16) return;
    int e  = t >> 4;
    int c4 = (t & 15) << 2;
    int s = srcv[e], d = dstv[e];
    float4 v = *(const float4*)(feat + (size_t)s * fstride + c4);
    float* a = acc + (size_t)d * 64 + c4;
    atomicAdd(a + 0, v.x);
    atomicAdd(a + 1, v.y);
    atomicAdd(a + 2, v.z);
    atomicAdd(a + 3, v.w);
    if (cnt != nullptr && (t & 15) == 0) atomicAdd(cnt + d, 1.0f);
}

// ---------------- fused GEMM  out[n][0..127] = act(in_row(n) @ W + b) ----
// LAYER==1: in_row = [agg1[n]*inv(n) | x[n]] (K=128), W = [W1_l ; W1_r],
//           bias=b1, relu, out = h [N,128]
// LAYER==2: in_row = h[n] (K=128), W = [W2_l | W2_r] (col concat),
//           no bias/relu, out = pq [N,128]
// Block: 512 threads, node tile 128. Thread tile: 4 nodes x 8 cols.
template <int LAYER>
__global__ __launch_bounds__(512) void sage_gemm(
    const float* __restrict__ inA, const float* __restrict__ inB,
    const float* __restrict__ cnt,
    const float* __restrict__ w0, const float* __restrict__ w1,
    const float* __restrict__ bias, float* __restrict__ out)
{
    __shared__ float s_in[128][132];   // +4 pad: 16B-aligned rows, spreads banks
    __shared__ float s_w[128][128];

    const int tid = threadIdx.x;
    const int n0  = blockIdx.x * 128;

    // ---- stage weights: 128x128 floats = 4096 float4, 8 per thread ----
    for (int i = tid; i < 4096; i += 512) {
        int k  = i >> 5;          // 0..127
        int j4 = (i & 31) << 2;   // 0..124
        const float* srcw;
        if (LAYER == 1) {         // rows of 128; k<64 -> W1_l, else W1_r
            srcw = (k < 64) ? (w0 + (size_t)k * 128 + j4)
                            : (w1 + (size_t)(k - 64) * 128 + j4);
        } else {                  // rows of 64; j<64 -> W2_l, else W2_r
            srcw = (j4 < 64) ? (w0 + (size_t)k * 64 + j4)
                             : (w1 + (size_t)k * 64 + (j4 - 64));
        }
        *(float4*)(&s_w[k][j4]) = *(const float4*)srcw;
    }

    // ---- stage input rows: 128 rows x 128 k; 4 threads/row, 8 float4 each
    {
        int r = tid >> 2;         // 0..127
        int q = tid & 3;
        int n = n0 + r;
        bool valid = (n < NN);
        float inv = 1.0f;
        if (LAYER == 1 && valid) inv = 1.0f / fmaxf(cnt[n], 1.0f);
        #pragma unroll
        for (int m = 0; m < 8; ++m) {
            int f  = q + 4 * m;   // float4 index 0..31 in the 128-float row
            int k4 = f << 2;
            float4 v = make_float4(0.f, 0.f, 0.f, 0.f);
            if (valid) {
                if (LAYER == 1) {
                    if (f < 16) {
                        v = *(const float4*)(inA + (size_t)n * 64 + k4);
                        v.x *= inv; v.y *= inv; v.z *= inv; v.w *= inv;
                    } else {
                        v = *(const float4*)(inB + (size_t)n * 64 + (k4 - 64));
                    }
                } else {
                    v = *(const float4*)(inA + (size_t)n * 128 + k4);
                }
            }
            *(float4*)(&s_in[r][k4]) = v;
        }
    }
    __syncthreads();

    // ---- compute: thread (ty,tx): nodes r0..r0+3, cols j0..j0+7 ----
    const int tx = tid & 15;
    const int ty = tid >> 4;
    const int j0 = tx << 3;
    const int r0 = ty << 2;

    float acc[4][8];
    #pragma unroll
    for (int i = 0; i < 4; ++i)
        #pragma unroll
        for (int j = 0; j < 8; ++j) acc[i][j] = 0.f;

    #pragma unroll 4
    for (int k = 0; k < 128; ++k) {
        float a0 = s_in[r0 + 0][k];
        float a1 = s_in[r0 + 1][k];
        float a2 = s_in[r0 + 2][k];
        float a3 = s_in[r0 + 3][k];
        float4 wa = *(const float4*)(&s_w[k][j0]);
        float4 wb = *(const float4*)(&s_w[k][j0 + 4]);
        float w[8] = {wa.x, wa.y, wa.z, wa.w, wb.x, wb.y, wb.z, wb.w};
        float a[4] = {a0, a1, a2, a3};
        #pragma unroll
        for (int i = 0; i < 4; ++i)
            #pragma unroll
            for (int j = 0; j < 8; ++j)
                acc[i][j] = fmaf(a[i], w[j], acc[i][j]);
    }

    // ---- epilogue ----
    float b[8];
    #pragma unroll
    for (int j = 0; j < 8; ++j) b[j] = (LAYER == 1) ? bias[j0 + j] : 0.f;

    #pragma unroll
    for (int i = 0; i < 4; ++i) {
        int n = n0 + r0 + i;
        if (n >= NN) break;
        float o[8];
        #pragma unroll
        for (int j = 0; j < 8; ++j) {
            float v = acc[i][j] + b[j];
            o[j] = (LAYER == 1) ? fmaxf(v, 0.f) : v;
        }
        *(float4*)(out + (size_t)n * 128 + j0)     = make_float4(o[0], o[1], o[2], o[3]);
        *(float4*)(out + (size_t)n * 128 + j0 + 4) = make_float4(o[4], o[5], o[6], o[7]);
    }
}

// ---------------- final: out = out*inv + q + b2 ----------------
__global__ __launch_bounds__(256) void sage_final(
    const float* __restrict__ pq, const float* __restrict__ cnt,
    const float* __restrict__ b2, float* __restrict__ out)
{
    int t = blockIdx.x * 256 + threadIdx.x;   // NN*16 float4s
    if (t >= NN * 16) return;
    int n  = t >> 4;
    int c4 = (t & 15) << 2;
    float inv = 1.0f / fmaxf(cnt[n], 1.0f);
    float4 a = *(float4*)(out + (size_t)n * 64 + c4);
    float4 q = *(const float4*)(pq + (size_t)n * 128 + 64 + c4);
    float4 b = *(const float4*)(b2 + c4);
    a.x = a.x * inv + q.x + b.x;
    a.y = a.y * inv + q.y + b.y;
    a.z = a.z * inv + q.z + b.z;
    a.w = a.w * inv + q.w + b.w;
    *(float4*)(out + (size_t)n * 64 + c4) = a;
}

extern "C" void kernel_launch(void* const* d_in, const int* in_sizes, int n_in,
                              void* d_out, int out_size, void* d_ws, size_t ws_size,
                              hipStream_t stream)
{
    const float* x    = (const float*)d_in[0];
    const int*   ei   = (const int*)d_in[1];    // [2, NE]
    const float* W1_l = (const float*)d_in[2];
    const float* b1   = (const float*)d_in[3];
    const float* W1_r = (const float*)d_in[4];
    const float* W2_l = (const float*)d_in[5];
    const float* b2   = (const float*)d_in[6];
    const float* W2_r = (const float*)d_in[7];

    float* out = (float*)d_out;
    float* ws  = (float*)d_ws;

    const int* srcv = ei;
    const int* dstv = ei + NE;

    float* cnt = ws + OFF_CNT;
    float* h   = ws + OFF_H;
    float* agg = ws + OFF_AGG;
    float* pq  = ws + OFF_PQ;

    // zero the atomic-accumulated buffers (required every call: harness does
    // not re-poison between replays, and we accumulate with atomics)
    hipMemsetAsync(cnt, 0, (size_t)NN * 4, stream);
    hipMemsetAsync(agg, 0, (size_t)NN * 64 * 4, stream);
    hipMemsetAsync(out, 0, (size_t)NN * 64 * 4, stream);

    // layer 1: agg1 = scatter_sum(x[src] -> dst), cnt = degrees
    sage_scatter<<<(NE * 16 + 255) / 256, 256, 0, stream>>>(srcv, dstv, x, 64, agg, cnt);
    // h = relu([agg1*inv | x] @ [W1_l ; W1_r] + b1)
    sage_gemm<1><<<(NN + 127) / 128, 512, 0, stream>>>(agg, x, cnt, W1_l, W1_r, b1, h);
    // pq = h @ [W2_l | W2_r]   (p = cols 0..63, q = cols 64..127)
    sage_gemm<2><<<(NN + 127) / 128, 512, 0, stream>>>(h, nullptr, nullptr, W2_l, W2_r, nullptr, pq);
    // out = scatter_sum(p[src] -> dst)
    sage_scatter<<<(NE * 16 + 255) / 256, 256, 0, stream>>>(srcv, dstv, pq, 128, out, nullptr);
    // out = out*inv + q + b2
    sage_final<<<(NN * 16 + 255) / 256, 256, 0, stream>>>(pq, cnt, b2, out);
}

// Round 2
// 409.276 us; speedup vs baseline: 5.7704x; 5.7704x over previous
//
#include <hip/hip_runtime.h>

#define NN 100000
#define NE 1250000

// ---------------- workspace layout ----------------
// ints (4B units from start of ws):
//   deg/cursor @ 0        : 102400   (deg for hist/scan1; reused as cursor after scan1)
//   offs       @ 102400   : 102400   (needs NN+1 = 100001)
//   bsum       @ 204800   : 128
//   ssrc       @ 204928   : 1250000  (ends 1454928)
// floats (starting at int index 1454928; byte 5,819,712, 16B aligned):
//   h          @ fbase          : NN*128 = 12.8M
//   agg/pbuf   @ fbase + 12.8M  : NN*64  =  6.4M   (agg: gather1->gemm1; pbuf: gemm2->gather2)
// total = 5.82 MB + 76.8 MB = 82.6 MB
static constexpr size_t I_DEG  = 0;
static constexpr size_t I_OFFS = 102400;
static constexpr size_t I_BSUM = 204800;
static constexpr size_t I_SSRC = 204928;
static constexpr size_t I_FBASE = 1454928;          // float region starts here (int idx)
static constexpr size_t F_H    = 0;                  // relative to float base
static constexpr size_t F_AGG  = 12800000;

#define SCAN_NB 98   // ceil(100000/1024)

// ---------------- degree histogram ----------------
__global__ __launch_bounds__(256) void sage_hist(const int* __restrict__ dstv,
                                                 int* __restrict__ deg)
{
    int e = blockIdx.x * 256 + threadIdx.x;
    if (e < NE) atomicAdd(&deg[dstv[e]], 1);
}

// ---------------- scan (exclusive prefix sum over deg -> offs) ----------
__global__ __launch_bounds__(256) void sage_scan1(const int* __restrict__ deg,
                                                  int* __restrict__ offs,
                                                  int* __restrict__ bsum)
{
    __shared__ int s[256];
    const int b = blockIdx.x, t = threadIdx.x;
    const int base = b * 1024 + t * 4;
    int v0 = (base + 0 < NN) ? deg[base + 0] : 0;
    int v1 = (base + 1 < NN) ? deg[base + 1] : 0;
    int v2 = (base + 2 < NN) ? deg[base + 2] : 0;
    int v3 = (base + 3 < NN) ? deg[base + 3] : 0;
    int local = v0 + v1 + v2 + v3;
    s[t] = local;
    __syncthreads();
    for (int d = 1; d < 256; d <<= 1) {
        int x = (t >= d) ? s[t - d] : 0;
        __syncthreads();
        s[t] += x;
        __syncthreads();
    }
    if (t == 255) bsum[b] = s[255];
    int run = s[t] - local;            // exclusive prefix of this thread's chunk
    if (base + 0 < NN) offs[base + 0] = run; run += v0;
    if (base + 1 < NN) offs[base + 1] = run; run += v1;
    if (base + 2 < NN) offs[base + 2] = run; run += v2;
    if (base + 3 < NN) offs[base + 3] = run;
}

__global__ __launch_bounds__(128) void sage_scan2(int* __restrict__ bsum)
{
    __shared__ int s[128];
    const int t = threadIdx.x;
    int v = (t < SCAN_NB) ? bsum[t] : 0;
    s[t] = v;
    __syncthreads();
    for (int d = 1; d < 128; d <<= 1) {
        int x = (t >= d) ? s[t - d] : 0;
        __syncthreads();
        s[t] += x;
        __syncthreads();
    }
    if (t < SCAN_NB) bsum[t] = s[t] - v;   // exclusive
}

__global__ __launch_bounds__(256) void sage_scan3(int* __restrict__ offs,
                                                  const int* __restrict__ bsum)
{
    int i = blockIdx.x * 256 + threadIdx.x;
    if (i < NN) offs[i] += bsum[i >> 10];
    if (i == 0) offs[NN] = NE;
}

// ---------------- counting-sort permute: ssrc = src sorted by dst --------
__global__ __launch_bounds__(256) void sage_permute(const int* __restrict__ srcv,
                                                    const int* __restrict__ dstv,
                                                    int* __restrict__ cursor,
                                                    int* __restrict__ ssrc)
{
    int e = blockIdx.x * 256 + threadIdx.x;
    if (e >= NE) return;
    int pos = atomicAdd(&cursor[dstv[e]], 1);
    ssrc[pos] = srcv[e];
}

// ---------------- gather-mean: 16 threads/node, register accumulate -----
// FUSE==0: dst[n*64+c] = mean_c            (layer-1 agg)
// FUSE==1: dst[n*64+c] = mean_c + dst[n*64+c] + b2[c]   (dst holds q from gemm2)
template <int FUSE>
__global__ __launch_bounds__(256) void sage_gather(
    const int* __restrict__ offs, const int* __restrict__ ssrc,
    const float* __restrict__ feat,
    const float* __restrict__ b2,
    float* __restrict__ dst)
{
    int t = blockIdx.x * 256 + threadIdx.x;
    int n = t >> 4;
    if (n >= NN) return;
    const int c4 = (t & 15) << 2;
    const int e0 = offs[n], e1 = offs[n + 1];

    float4 acc = make_float4(0.f, 0.f, 0.f, 0.f);
    int e = e0;
    for (; e + 2 <= e1; e += 2) {            // 2-edge ILP
        int s0 = ssrc[e], s1 = ssrc[e + 1];
        float4 a = *(const float4*)(feat + (size_t)s0 * 64 + c4);
        float4 b = *(const float4*)(feat + (size_t)s1 * 64 + c4);
        acc.x += a.x + b.x; acc.y += a.y + b.y;
        acc.z += a.z + b.z; acc.w += a.w + b.w;
    }
    if (e < e1) {
        int s0 = ssrc[e];
        float4 a = *(const float4*)(feat + (size_t)s0 * 64 + c4);
        acc.x += a.x; acc.y += a.y; acc.z += a.z; acc.w += a.w;
    }
    const float inv = 1.0f / (float)max(e1 - e0, 1);
    acc.x *= inv; acc.y *= inv; acc.z *= inv; acc.w *= inv;

    float* o = dst + (size_t)n * 64 + c4;
    if (FUSE) {
        float4 q = *(const float4*)o;                 // q written by gemm2
        float4 bb = *(const float4*)(b2 + c4);
        acc.x += q.x + bb.x; acc.y += q.y + bb.y;
        acc.z += q.z + bb.z; acc.w += q.w + bb.w;
    }
    *(float4*)o = acc;
}

// ---------------- fused GEMM ----------------
// LAYER==1: in_row = [agg_mean[n] | x[n]] (K=128), W=[W1_l;W1_r], +b1, relu,
//           outLo = h [N,128]
// LAYER==2: in_row = h[n] (K=128), W=[W2_l|W2_r]; cols 0..63 -> outLo (p, [N,64]),
//           cols 64..127 -> outHi (q, [N,64])
template <int LAYER>
__global__ __launch_bounds__(512) void sage_gemm(
    const float* __restrict__ inA, const float* __restrict__ inB,
    const float* __restrict__ w0, const float* __restrict__ w1,
    const float* __restrict__ bias,
    float* __restrict__ outLo, float* __restrict__ outHi)
{
    __shared__ float s_in[128][132];
    __shared__ float s_w[128][128];

    const int tid = threadIdx.x;
    const int n0  = blockIdx.x * 128;

    for (int i = tid; i < 4096; i += 512) {
        int k  = i >> 5;
        int j4 = (i & 31) << 2;
        const float* srcw;
        if (LAYER == 1) {
            srcw = (k < 64) ? (w0 + (size_t)k * 128 + j4)
                            : (w1 + (size_t)(k - 64) * 128 + j4);
        } else {
            srcw = (j4 < 64) ? (w0 + (size_t)k * 64 + j4)
                             : (w1 + (size_t)k * 64 + (j4 - 64));
        }
        *(float4*)(&s_w[k][j4]) = *(const float4*)srcw;
    }

    {
        int r = tid >> 2;
        int q = tid & 3;
        int n = n0 + r;
        bool valid = (n < NN);
        #pragma unroll
        for (int m = 0; m < 8; ++m) {
            int f  = q + 4 * m;
            int k4 = f << 2;
            float4 v = make_float4(0.f, 0.f, 0.f, 0.f);
            if (valid) {
                if (LAYER == 1) {
                    v = (f < 16) ? *(const float4*)(inA + (size_t)n * 64 + k4)
                                 : *(const float4*)(inB + (size_t)n * 64 + (k4 - 64));
                } else {
                    v = *(const float4*)(inA + (size_t)n * 128 + k4);
                }
            }
            *(float4*)(&s_in[r][k4]) = v;
        }
    }
    __syncthreads();

    const int tx = tid & 15;
    const int ty = tid >> 4;
    const int j0 = tx << 3;
    const int r0 = ty << 2;

    float acc[4][8];
    #pragma unroll
    for (int i = 0; i < 4; ++i)
        #pragma unroll
        for (int j = 0; j < 8; ++j) acc[i][j] = 0.f;

    #pragma unroll 4
    for (int k = 0; k < 128; ++k) {
        float a[4] = {s_in[r0 + 0][k], s_in[r0 + 1][k],
                      s_in[r0 + 2][k], s_in[r0 + 3][k]};
        float4 wa = *(const float4*)(&s_w[k][j0]);
        float4 wb = *(const float4*)(&s_w[k][j0 + 4]);
        float w[8] = {wa.x, wa.y, wa.z, wa.w, wb.x, wb.y, wb.z, wb.w};
        #pragma unroll
        for (int i = 0; i < 4; ++i)
            #pragma unroll
            for (int j = 0; j < 8; ++j)
                acc[i][j] = fmaf(a[i], w[j], acc[i][j]);
    }

    float b[8];
    #pragma unroll
    for (int j = 0; j < 8; ++j) b[j] = (LAYER == 1) ? bias[j0 + j] : 0.f;

    #pragma unroll
    for (int i = 0; i < 4; ++i) {
        int n = n0 + r0 + i;
        if (n >= NN) break;
        float o[8];
        #pragma unroll
        for (int j = 0; j < 8; ++j) {
            float v = acc[i][j] + b[j];
            o[j] = (LAYER == 1) ? fmaxf(v, 0.f) : v;
        }
        float4 lo = make_float4(o[0], o[1], o[2], o[3]);
        float4 hi = make_float4(o[4], o[5], o[6], o[7]);
        if (LAYER == 1) {
            *(float4*)(outLo + (size_t)n * 128 + j0)     = lo;
            *(float4*)(outLo + (size_t)n * 128 + j0 + 4) = hi;
        } else {
            float* d = (j0 < 64) ? (outLo + (size_t)n * 64 + j0)
                                 : (outHi + (size_t)n * 64 + (j0 - 64));
            *(float4*)(d)     = lo;
            *(float4*)(d + 4) = hi;
        }
    }
}

extern "C" void kernel_launch(void* const* d_in, const int* in_sizes, int n_in,
                              void* d_out, int out_size, void* d_ws, size_t ws_size,
                              hipStream_t stream)
{
    const float* x    = (const float*)d_in[0];
    const int*   ei   = (const int*)d_in[1];
    const float* W1_l = (const float*)d_in[2];
    const float* b1   = (const float*)d_in[3];
    const float* W1_r = (const float*)d_in[4];
    const float* W2_l = (const float*)d_in[5];
    const float* b2   = (const float*)d_in[6];
    const float* W2_r = (const float*)d_in[7];

    float* out = (float*)d_out;
    int*   wi  = (int*)d_ws;

    const int* srcv = ei;
    const int* dstv = ei + NE;

    int* deg    = wi + I_DEG;      // also reused as cursor after scan1
    int* offs   = wi + I_OFFS;
    int* bsum   = wi + I_BSUM;
    int* ssrc   = wi + I_SSRC;
    float* fb   = (float*)(wi + I_FBASE);
    float* h    = fb + F_H;
    float* agg  = fb + F_AGG;      // layer-1 mean, later reused as pbuf (p = h@W2_l)

    // ---- CSR build (counting sort by dst) ----
    hipMemsetAsync(deg, 0, (size_t)NN * 4, stream);
    sage_hist   <<<(NE + 255) / 256, 256, 0, stream>>>(dstv, deg);
    sage_scan1  <<<SCAN_NB, 256, 0, stream>>>(deg, offs, bsum);
    sage_scan2  <<<1, 128, 0, stream>>>(bsum);
    sage_scan3  <<<(NN + 255) / 256 + 1, 256, 0, stream>>>(offs, bsum);
    hipMemcpyAsync(deg, offs, (size_t)NN * 4, hipMemcpyDeviceToDevice, stream); // cursor
    sage_permute<<<(NE + 255) / 256, 256, 0, stream>>>(srcv, dstv, deg, ssrc);

    // ---- layer 1: agg = mean_{j in N(i)} x_j ; h = relu([agg|x] @ W1 + b1)
    sage_gather<0><<<(NN * 16 + 255) / 256, 256, 0, stream>>>(offs, ssrc, x, nullptr, agg);
    sage_gemm<1><<<(NN + 127) / 128, 512, 0, stream>>>(agg, x, W1_l, W1_r, b1, h, nullptr);

    // ---- layer 2: p = h@W2_l -> agg(pbuf), q = h@W2_r -> out
    sage_gemm<2><<<(NN + 127) / 128, 512, 0, stream>>>(h, nullptr, W2_l, W2_r, nullptr, agg, out);
    // out = mean_{j in N(i)} p_j + q + b2
    sage_gather<1><<<(NN * 16 + 255) / 256, 256, 0, stream>>>(offs, ssrc, agg, b2, out);
}

// Round 3
// 246.165 us; speedup vs baseline: 9.5940x; 1.6626x over previous
//
#include <hip/hip_runtime.h>

#define NN 100000
#define NE 1250000

typedef __attribute__((ext_vector_type(8))) short short8;
typedef __attribute__((ext_vector_type(4))) float f32x4;

// ---------------- workspace layout ----------------
// int units:
//   deg   @ 0        : 102400
//   offs  @ 102400   : 102400 (needs NN+1)
//   bsum  @ 204800   : 256
//   rank  @ 205056   : 1250000
//   ssrc  @ 1455056  : 1250000  -> ends 2705056 (byte 10,820,224; 16B aligned)
// ushort units (base = 2705056*2 = 5410112):
//   xb  @ 0          : NN*64
//   agg @ 6400000    : NN*64   (layer-1 mean, bf16; reused as p after gemm2? no - separate)
//   h   @ 12800000   : NN*128
//   p   @ 25600000   : NN*64
//   Wt1 @ 32000000   : 16384
//   Wt2 @ 32016384   : 16384  -> ends 32032768 (64.1 MB)  total ~74.9 MB
static constexpr size_t I_DEG  = 0;
static constexpr size_t I_OFFS = 102400;
static constexpr size_t I_BSUM = 204800;
static constexpr size_t I_RANK = 205056;
static constexpr size_t I_SSRC = 1455056;
static constexpr size_t U_BASE = 5410112;
static constexpr size_t U_XB   = 0;
static constexpr size_t U_AGG  = 6400000;
static constexpr size_t U_H    = 12800000;
static constexpr size_t U_P    = 25600000;
static constexpr size_t U_WT1  = 32000000;
static constexpr size_t U_WT2  = 32016384;

#define SCAN_NB 98

__device__ __forceinline__ float bf2f(unsigned short u) {
    unsigned int v = ((unsigned int)u) << 16;
    return __builtin_bit_cast(float, v);
}
__device__ __forceinline__ unsigned short f2bf(float f) {
    unsigned int u = __builtin_bit_cast(unsigned int, f);
    unsigned int r = (u + 0x7fffu + ((u >> 16) & 1u)) >> 16;
    return (unsigned short)r;
}

// ---------------- x -> bf16 ----------------
__global__ __launch_bounds__(256) void conv_x(const float* __restrict__ x,
                                              unsigned short* __restrict__ xb)
{
    int t = blockIdx.x * 256 + threadIdx.x;
    if (t >= NN * 16) return;
    float4 v = ((const float4*)x)[t];
    *(ushort4*)(xb + (size_t)t * 4) =
        make_ushort4(f2bf(v.x), f2bf(v.y), f2bf(v.z), f2bf(v.w));
}

// ---------------- weight prep: Wt[j][k] = W[k][j], bf16 ----------------
__global__ __launch_bounds__(256) void prep_w(
    const float* __restrict__ W1l, const float* __restrict__ W1r,
    const float* __restrict__ W2l, const float* __restrict__ W2r,
    unsigned short* __restrict__ Wt1, unsigned short* __restrict__ Wt2)
{
    int t = blockIdx.x * 256 + threadIdx.x;
    if (t >= 16384) return;
    int j = t >> 7, k = t & 127;
    float w1 = (k < 64) ? W1l[(size_t)k * 128 + j] : W1r[(size_t)(k - 64) * 128 + j];
    Wt1[(size_t)j * 128 + k] = f2bf(w1);
    float w2 = (j < 64) ? W2l[(size_t)k * 64 + j] : W2r[(size_t)k * 64 + (j - 64)];
    Wt2[(size_t)j * 128 + k] = f2bf(w2);
}

// ---------------- degree histogram + per-edge rank ----------------
__global__ __launch_bounds__(256) void sage_hist(const int* __restrict__ dstv,
                                                 int* __restrict__ deg,
                                                 int* __restrict__ rank)
{
    int t = blockIdx.x * 256 + threadIdx.x;
    int e0 = t * 4;
    if (e0 >= NE) return;
    int4 d = *(const int4*)(dstv + e0);
    rank[e0 + 0] = atomicAdd(&deg[d.x], 1);
    rank[e0 + 1] = atomicAdd(&deg[d.y], 1);
    rank[e0 + 2] = atomicAdd(&deg[d.z], 1);
    rank[e0 + 3] = atomicAdd(&deg[d.w], 1);
}

// ---------------- scan ----------------
__global__ __launch_bounds__(256) void sage_scan1(const int* __restrict__ deg,
                                                  int* __restrict__ offs,
                                                  int* __restrict__ bsum)
{
    __shared__ int s[256];
    const int b = blockIdx.x, t = threadIdx.x;
    const int base = b * 1024 + t * 4;
    int v0 = (base + 0 < NN) ? deg[base + 0] : 0;
    int v1 = (base + 1 < NN) ? deg[base + 1] : 0;
    int v2 = (base + 2 < NN) ? deg[base + 2] : 0;
    int v3 = (base + 3 < NN) ? deg[base + 3] : 0;
    int local = v0 + v1 + v2 + v3;
    s[t] = local;
    __syncthreads();
    for (int d = 1; d < 256; d <<= 1) {
        int x = (t >= d) ? s[t - d] : 0;
        __syncthreads();
        s[t] += x;
        __syncthreads();
    }
    if (t == 255) bsum[b] = s[255];
    int run = s[t] - local;
    if (base + 0 < NN) offs[base + 0] = run; run += v0;
    if (base + 1 < NN) offs[base + 1] = run; run += v1;
    if (base + 2 < NN) offs[base + 2] = run; run += v2;
    if (base + 3 < NN) offs[base + 3] = run;
}

__global__ __launch_bounds__(128) void sage_scan2(int* __restrict__ bsum)
{
    __shared__ int s[128];
    const int t = threadIdx.x;
    int v = (t < SCAN_NB) ? bsum[t] : 0;
    s[t] = v;
    __syncthreads();
    for (int d = 1; d < 128; d <<= 1) {
        int x = (t >= d) ? s[t - d] : 0;
        __syncthreads();
        s[t] += x;
        __syncthreads();
    }
    if (t < SCAN_NB) bsum[t] = s[t] - v;
}

__global__ __launch_bounds__(256) void sage_scan3(int* __restrict__ offs,
                                                  const int* __restrict__ bsum)
{
    int i = blockIdx.x * 256 + threadIdx.x;
    if (i < NN) offs[i] += bsum[i >> 10];
    if (i == 0) offs[NN] = NE;
}

// ---------------- permute (no atomics): ssrc[offs[dst]+rank] = src ------
__global__ __launch_bounds__(256) void sage_permute(
    const int* __restrict__ srcv, const int* __restrict__ dstv,
    const int* __restrict__ rank, const int* __restrict__ offs,
    int* __restrict__ ssrc)
{
    int t = blockIdx.x * 256 + threadIdx.x;
    int e0 = t * 4;
    if (e0 >= NE) return;
    int4 s = *(const int4*)(srcv + e0);
    int4 d = *(const int4*)(dstv + e0);
    int4 r = *(const int4*)(rank + e0);
    ssrc[offs[d.x] + r.x] = s.x;
    ssrc[offs[d.y] + r.y] = s.y;
    ssrc[offs[d.z] + r.z] = s.z;
    ssrc[offs[d.w] + r.w] = s.w;
}

// ---------------- gather-mean over bf16 features ----------------
// FUSE==0: aggb[n][c] = bf16(mean)
// FUSE==1: out[n][c]  = mean + out[n][c](=q) + b2[c]   (f32)
template <int FUSE>
__global__ __launch_bounds__(256) void sage_gather(
    const int* __restrict__ offs, const int* __restrict__ ssrc,
    const unsigned short* __restrict__ feat,
    const float* __restrict__ b2,
    unsigned short* __restrict__ aggb, float* __restrict__ out)
{
    int t = blockIdx.x * 256 + threadIdx.x;
    int n = t >> 4;
    if (n >= NN) return;
    const int c4 = (t & 15) << 2;
    const int e0 = offs[n], e1 = offs[n + 1];

    float ax = 0.f, ay = 0.f, az = 0.f, aw = 0.f;
    int e = e0;
    for (; e + 2 <= e1; e += 2) {
        int s0 = ssrc[e], s1 = ssrc[e + 1];
        ushort4 u = *(const ushort4*)(feat + (size_t)s0 * 64 + c4);
        ushort4 v = *(const ushort4*)(feat + (size_t)s1 * 64 + c4);
        ax += bf2f(u.x) + bf2f(v.x);
        ay += bf2f(u.y) + bf2f(v.y);
        az += bf2f(u.z) + bf2f(v.z);
        aw += bf2f(u.w) + bf2f(v.w);
    }
    if (e < e1) {
        int s0 = ssrc[e];
        ushort4 u = *(const ushort4*)(feat + (size_t)s0 * 64 + c4);
        ax += bf2f(u.x); ay += bf2f(u.y); az += bf2f(u.z); aw += bf2f(u.w);
    }
    int dg = e1 - e0;
    const float inv = 1.0f / (float)(dg > 0 ? dg : 1);
    ax *= inv; ay *= inv; az *= inv; aw *= inv;

    if (FUSE == 0) {
        *(ushort4*)(aggb + (size_t)n * 64 + c4) =
            make_ushort4(f2bf(ax), f2bf(ay), f2bf(az), f2bf(aw));
    } else {
        float* o = out + (size_t)n * 64 + c4;
        float4 q = *(const float4*)o;
        float4 bb = *(const float4*)(b2 + c4);
        float4 res = make_float4(ax + q.x + bb.x, ay + q.y + bb.y,
                                 az + q.z + bb.z, aw + q.w + bb.w);
        *(float4*)o = res;
    }
}

// ---------------- MFMA GEMM (no LDS) ----------------
// LAYER==1: A-row n = [agg[n] | xb[n]] (K=128 bf16), Wt=Wt1 ([col][k]),
//           h[n][col] = bf16(relu(acc + b1[col]))
// LAYER==2: A-row n = h[n] (K=128 bf16), Wt=Wt2;
//           col<64 -> p[n][col] bf16 ; col>=64 -> out[n][col-64] = acc (f32, =q)
template <int LAYER>
__global__ __launch_bounds__(512) void sage_gemm(
    const unsigned short* __restrict__ inA, const unsigned short* __restrict__ inB,
    const unsigned short* __restrict__ Wt, const float* __restrict__ bias,
    unsigned short* __restrict__ outLo, float* __restrict__ outHi)
{
    const int tid  = threadIdx.x;
    const int lane = tid & 63;
    const int wid  = tid >> 6;                 // 0..7
    const int r0   = blockIdx.x * 128 + wid * 16;
    const int lrow = lane & 15;
    const int lk   = lane >> 4;                // 0..3

    int arow = r0 + lrow;
    if (arow >= NN) arow = NN - 1;

    short8 a[4];
    #pragma unroll
    for (int kk = 0; kk < 4; ++kk) {
        int k0 = kk * 32 + lk * 8;
        const unsigned short* ap;
        if (LAYER == 1)
            ap = (k0 < 64) ? (inA + (size_t)arow * 64 + k0)
                           : (inB + (size_t)arow * 64 + (k0 - 64));
        else
            ap = inA + (size_t)arow * 128 + k0;
        a[kk] = *(const short8*)ap;
    }

    f32x4 acc[8];
    #pragma unroll
    for (int c = 0; c < 8; ++c) acc[c] = (f32x4){0.f, 0.f, 0.f, 0.f};

    #pragma unroll
    for (int c = 0; c < 8; ++c) {
        #pragma unroll
        for (int kk = 0; kk < 4; ++kk) {
            short8 b = *(const short8*)(Wt + (size_t)(c * 16 + lrow) * 128 + kk * 32 + lk * 8);
            acc[c] = __builtin_amdgcn_mfma_f32_16x16x32_bf16(a[kk], b, acc[c], 0, 0, 0);
        }
    }

    // D layout: row = lk*4 + ri (within wave's 16-row block), col = c*16 + lrow
    #pragma unroll
    for (int c = 0; c < 8; ++c) {
        int col = c * 16 + lrow;
        float bv = (LAYER == 1) ? bias[col] : 0.f;
        #pragma unroll
        for (int ri = 0; ri < 4; ++ri) {
            int row = r0 + lk * 4 + ri;
            if (row >= NN) continue;
            float v = acc[c][ri] + bv;
            if (LAYER == 1) {
                v = fmaxf(v, 0.f);
                outLo[(size_t)row * 128 + col] = f2bf(v);
            } else {
                if (col < 64) outLo[(size_t)row * 64 + col] = f2bf(v);
                else          outHi[(size_t)row * 64 + (col - 64)] = v;
            }
        }
    }
}

extern "C" void kernel_launch(void* const* d_in, const int* in_sizes, int n_in,
                              void* d_out, int out_size, void* d_ws, size_t ws_size,
                              hipStream_t stream)
{
    const float* x    = (const float*)d_in[0];
    const int*   ei   = (const int*)d_in[1];
    const float* W1_l = (const float*)d_in[2];
    const float* b1   = (const float*)d_in[3];
    const float* W1_r = (const float*)d_in[4];
    const float* W2_l = (const float*)d_in[5];
    const float* b2   = (const float*)d_in[6];
    const float* W2_r = (const float*)d_in[7];

    float* out = (float*)d_out;
    int*   wi  = (int*)d_ws;

    const int* srcv = ei;
    const int* dstv = ei + NE;

    int* deg  = wi + I_DEG;
    int* offs = wi + I_OFFS;
    int* bsum = wi + I_BSUM;
    int* rank = wi + I_RANK;
    int* ssrc = wi + I_SSRC;
    unsigned short* ub  = (unsigned short*)d_ws + U_BASE;
    unsigned short* xb  = ub + U_XB;
    unsigned short* agg = ub + U_AGG;
    unsigned short* h   = ub + U_H;
    unsigned short* p   = ub + U_P;
    unsigned short* Wt1 = ub + U_WT1;
    unsigned short* Wt2 = ub + U_WT2;

    hipMemsetAsync(deg, 0, (size_t)NN * 4, stream);

    conv_x <<<(NN * 16 + 255) / 256, 256, 0, stream>>>(x, xb);
    prep_w <<<64, 256, 0, stream>>>(W1_l, W1_r, W2_l, W2_r, Wt1, Wt2);

    sage_hist   <<<(NE / 4 + 255) / 256, 256, 0, stream>>>(dstv, deg, rank);
    sage_scan1  <<<SCAN_NB, 256, 0, stream>>>(deg, offs, bsum);
    sage_scan2  <<<1, 128, 0, stream>>>(bsum);
    sage_scan3  <<<(NN + 255) / 256 + 1, 256, 0, stream>>>(offs, bsum);
    sage_permute<<<(NE / 4 + 255) / 256, 256, 0, stream>>>(srcv, dstv, rank, offs, ssrc);

    // layer 1
    sage_gather<0><<<(NN * 16 + 255) / 256, 256, 0, stream>>>(offs, ssrc, xb, nullptr, agg, nullptr);
    sage_gemm<1>  <<<(NN + 127) / 128, 512, 0, stream>>>(agg, xb, Wt1, b1, h, nullptr);

    // layer 2: p (bf16) + q (f32 -> out)
    sage_gemm<2>  <<<(NN + 127) / 128, 512, 0, stream>>>(h, nullptr, Wt2, nullptr, p, out);
    sage_gather<1><<<(NN * 16 + 255) / 256, 256, 0, stream>>>(offs, ssrc, p, b2, nullptr, out);
}

// Round 4
// 213.083 us; speedup vs baseline: 11.0835x; 1.1553x over previous
//
#include <hip/hip_runtime.h>

#define NN 100000
#define NE 1250000

#define NBLK1 320      // blocks in pass0/pass1
#define CHUNK 3907     // ceil(NE / NBLK1)
#define NBUK  196      // ceil(NN / 512), bucket = dst >> 9
#define CAP   8192     // pass-2 LDS edge capacity (mean 6378, 26 sigma margin)

typedef __attribute__((ext_vector_type(8))) short short8;
typedef __attribute__((ext_vector_type(4))) float f32x4;

// ---------------- workspace layout ----------------
// int units:
//   blockHist  @ 0       : 196*320 = 62720   [bucket][blk]
//   bucketTot  @ 62720   : 256
//   bucketBase @ 62976   : 256 (needs 197)
//   offs       @ 63232   : 100001 -> 163233 (pad 163236)
//   pairs      @ 163236  : 1250000 -> 1413236
//   ssrc       @ 1413236 : 1250000 -> 2663236
// ushort units (base = 2663236*2 = 5326472; byte 10,652,944 = 16B aligned):
//   xb  @ 0        : 6,400,000
//   agg @ 6400000  : 6,400,000
//   h   @ 12800000 : 12,800,000
//   p   @ 25600000 : 6,400,000
//   Wt1 @ 32000000 : 16384
//   Wt2 @ 32016384 : 16384
// total ~74.7 MB
static constexpr size_t I_BH    = 0;
static constexpr size_t I_BT    = 62720;
static constexpr size_t I_BB    = 62976;
static constexpr size_t I_OFFS  = 63232;
static constexpr size_t I_PAIRS = 163236;
static constexpr size_t I_SSRC  = 1413236;
static constexpr size_t U_BASE  = 5326472;
static constexpr size_t U_XB    = 0;
static constexpr size_t U_AGG   = 6400000;
static constexpr size_t U_H     = 12800000;
static constexpr size_t U_P     = 25600000;
static constexpr size_t U_WT1   = 32000000;
static constexpr size_t U_WT2   = 32016384;

__device__ __forceinline__ float bf2f(unsigned int u16) {
    unsigned int v = u16 << 16;
    return __builtin_bit_cast(float, v);
}
__device__ __forceinline__ unsigned short f2bf(float f) {
    unsigned int u = __builtin_bit_cast(unsigned int, f);
    unsigned int r = (u + 0x7fffu + ((u >> 16) & 1u)) >> 16;
    return (unsigned short)r;
}

// ---------------- x -> bf16 ----------------
__global__ __launch_bounds__(256) void conv_x(const float* __restrict__ x,
                                              unsigned short* __restrict__ xb)
{
    int t = blockIdx.x * 256 + threadIdx.x;
    if (t >= NN * 16) return;
    float4 v = ((const float4*)x)[t];
    *(ushort4*)(xb + (size_t)t * 4) =
        make_ushort4(f2bf(v.x), f2bf(v.y), f2bf(v.z), f2bf(v.w));
}

// ---------------- weight prep: Wt[j][k] = W[k][j], bf16 ----------------
__global__ __launch_bounds__(256) void prep_w(
    const float* __restrict__ W1l, const float* __restrict__ W1r,
    const float* __restrict__ W2l, const float* __restrict__ W2r,
    unsigned short* __restrict__ Wt1, unsigned short* __restrict__ Wt2)
{
    int t = blockIdx.x * 256 + threadIdx.x;
    if (t >= 16384) return;
    int j = t >> 7, k = t & 127;
    float w1 = (k < 64) ? W1l[(size_t)k * 128 + j] : W1r[(size_t)(k - 64) * 128 + j];
    Wt1[(size_t)j * 128 + k] = f2bf(w1);
    float w2 = (j < 64) ? W2l[(size_t)k * 64 + j] : W2r[(size_t)k * 64 + (j - 64)];
    Wt2[(size_t)j * 128 + k] = f2bf(w2);
}

// ---------------- pass 0: per-block bucket histogram (LDS only) --------
__global__ __launch_bounds__(512) void p0_hist(const int* __restrict__ dstv,
                                               int* __restrict__ blockHist)
{
    __shared__ int hist[NBUK];
    const int t = threadIdx.x, b = blockIdx.x;
    for (int i = t; i < NBUK; i += 512) hist[i] = 0;
    __syncthreads();
    const int start = b * CHUNK;
    const int end   = min(start + CHUNK, NE);
    for (int e = start + t; e < end; e += 512)
        atomicAdd(&hist[dstv[e] >> 9], 1);
    __syncthreads();
    for (int i = t; i < NBUK; i += 512)
        blockHist[(size_t)i * NBLK1 + b] = hist[i];
}

// ---------------- scan A: per-bucket exclusive scan over blocks --------
__global__ __launch_bounds__(512) void p_scanA(int* __restrict__ blockHist,
                                               int* __restrict__ bucketTot)
{
    __shared__ int s[512];
    const int b = blockIdx.x, t = threadIdx.x;
    int v = (t < NBLK1) ? blockHist[(size_t)b * NBLK1 + t] : 0;
    s[t] = v;
    __syncthreads();
    for (int d = 1; d < 512; d <<= 1) {
        int x = (t >= d) ? s[t - d] : 0;
        __syncthreads();
        s[t] += x;
        __syncthreads();
    }
    if (t < NBLK1) blockHist[(size_t)b * NBLK1 + t] = s[t] - v;  // exclusive
    if (t == NBLK1 - 1) bucketTot[b] = s[t];
}

// ---------------- scan B: exclusive scan of bucket totals --------------
__global__ __launch_bounds__(256) void p_scanB(const int* __restrict__ bucketTot,
                                               int* __restrict__ bucketBase,
                                               int* __restrict__ offs)
{
    __shared__ int s[256];
    const int t = threadIdx.x;
    int v = (t < NBUK) ? bucketTot[t] : 0;
    s[t] = v;
    __syncthreads();
    for (int d = 1; d < 256; d <<= 1) {
        int x = (t >= d) ? s[t - d] : 0;
        __syncthreads();
        s[t] += x;
        __syncthreads();
    }
    if (t < NBUK) bucketBase[t] = s[t] - v;
    if (t == 0) { bucketBase[NBUK] = NE; offs[NN] = NE; }
}

// ---------------- pass 1: bucket-grouped scatter of packed edges -------
__global__ __launch_bounds__(512) void p1_scatter(
    const int* __restrict__ srcv, const int* __restrict__ dstv,
    const int* __restrict__ blockHist, const int* __restrict__ bucketBase,
    int* __restrict__ pairs)
{
    __shared__ int cur[NBUK];
    const int t = threadIdx.x, b = blockIdx.x;
    for (int i = t; i < NBUK; i += 512)
        cur[i] = bucketBase[i] + blockHist[(size_t)i * NBLK1 + b];
    __syncthreads();
    const int start = b * CHUNK;
    const int end   = min(start + CHUNK, NE);
    for (int e = start + t; e < end; e += 512) {
        int d = dstv[e], s = srcv[e];
        int pos = atomicAdd(&cur[d >> 9], 1);      // LDS atomic
        pairs[pos] = s | ((d & 511) << 17);
    }
}

// ---------------- pass 2: per-bucket counting sort (LDS) ---------------
__global__ __launch_bounds__(1024) void p2_sort(
    const int* __restrict__ pairs, const int* __restrict__ bucketBase,
    int* __restrict__ offs, int* __restrict__ ssrc)
{
    __shared__ int buf[CAP];
    __shared__ int hist[512];
    const int b = blockIdx.x, t = threadIdx.x;
    const int base = bucketBase[b];
    const int m    = bucketBase[b + 1] - base;
    const bool fits = (m <= CAP);

    if (t < 512) hist[t] = 0;
    __syncthreads();
    for (int i = t; i < m; i += 1024) {
        int v = pairs[base + i];
        if (fits) buf[i] = v;
        atomicAdd(&hist[v >> 17], 1);
    }
    __syncthreads();

    int ov = (t < 512) ? hist[t] : 0;
    __syncthreads();
    for (int d = 1; d < 512; d <<= 1) {
        int x = 0;
        if (t < 512 && t >= d) x = hist[t - d];
        __syncthreads();
        if (t < 512) hist[t] += x;
        __syncthreads();
    }
    int excl = 0;
    if (t < 512) excl = hist[t] - ov;
    __syncthreads();
    if (t < 512) {
        hist[t] = excl;                            // becomes cursor
        int n = b * 512 + t;
        if (n < NN) offs[n] = base + excl;
    }
    __syncthreads();
    for (int i = t; i < m; i += 1024) {
        int v = fits ? buf[i] : pairs[base + i];
        int pos = atomicAdd(&hist[v >> 17], 1);    // LDS atomic
        ssrc[base + pos] = v & 0x1FFFF;
    }
}

// ---------------- gather-mean: 16 lanes/node = 8 ch x 2 edge-parities --
// FUSE==0: aggb[n][c] = bf16(mean)
// FUSE==1: out[n][c]  = mean + out[n][c](=q) + b2[c]   (f32)
template <int FUSE>
__global__ __launch_bounds__(256) void sage_gather(
    const int* __restrict__ offs, const int* __restrict__ ssrc,
    const unsigned short* __restrict__ feat,
    const float* __restrict__ b2,
    unsigned short* __restrict__ aggb, float* __restrict__ out)
{
    const int t = blockIdx.x * 256 + threadIdx.x;   // NN*16 exact
    const int n    = t >> 4;
    const int l    = t & 15;
    const int epar = l >> 3;       // edge parity 0/1
    const int ch   = l & 7;        // 8 channels of 8 bf16 (16B)
    const int e0 = offs[n], e1 = offs[n + 1];

    float acc[8];
    #pragma unroll
    for (int j = 0; j < 8; ++j) acc[j] = 0.f;

    for (int e = e0 + epar; e < e1; e += 2) {
        int s = ssrc[e];
        uint4 u = *(const uint4*)(feat + (size_t)s * 64 + ch * 8);
        acc[0] += bf2f(u.x & 0xffffu); acc[1] += bf2f(u.x >> 16);
        acc[2] += bf2f(u.y & 0xffffu); acc[3] += bf2f(u.y >> 16);
        acc[4] += bf2f(u.z & 0xffffu); acc[5] += bf2f(u.z >> 16);
        acc[6] += bf2f(u.w & 0xffffu); acc[7] += bf2f(u.w >> 16);
    }
    #pragma unroll
    for (int j = 0; j < 8; ++j) acc[j] += __shfl_xor(acc[j], 8);
    if (epar) return;

    const int dg = e1 - e0;
    const float inv = 1.0f / (float)(dg > 0 ? dg : 1);
    #pragma unroll
    for (int j = 0; j < 8; ++j) acc[j] *= inv;

    if (FUSE == 0) {
        uint4 o;
        o.x = (unsigned)f2bf(acc[0]) | ((unsigned)f2bf(acc[1]) << 16);
        o.y = (unsigned)f2bf(acc[2]) | ((unsigned)f2bf(acc[3]) << 16);
        o.z = (unsigned)f2bf(acc[4]) | ((unsigned)f2bf(acc[5]) << 16);
        o.w = (unsigned)f2bf(acc[6]) | ((unsigned)f2bf(acc[7]) << 16);
        *(uint4*)(aggb + (size_t)n * 64 + ch * 8) = o;
    } else {
        float* o = out + (size_t)n * 64 + ch * 8;
        float4 q0 = *(const float4*)(o);
        float4 q1 = *(const float4*)(o + 4);
        float4 c0 = *(const float4*)(b2 + ch * 8);
        float4 c1 = *(const float4*)(b2 + ch * 8 + 4);
        *(float4*)(o)     = make_float4(acc[0] + q0.x + c0.x, acc[1] + q0.y + c0.y,
                                        acc[2] + q0.z + c0.z, acc[3] + q0.w + c0.w);
        *(float4*)(o + 4) = make_float4(acc[4] + q1.x + c1.x, acc[5] + q1.y + c1.y,
                                        acc[6] + q1.z + c1.z, acc[7] + q1.w + c1.w);
    }
}

// ---------------- MFMA GEMM (no LDS) ----------------
// LAYER==1: A-row n = [agg[n] | xb[n]] (K=128 bf16), Wt=Wt1 ([col][k]),
//           h[n][col] = bf16(relu(acc + b1[col]))
// LAYER==2: A-row n = h[n] (K=128 bf16), Wt=Wt2;
//           col<64 -> p[n][col] bf16 ; col>=64 -> out[n][col-64] = acc (f32, =q)
template <int LAYER>
__global__ __launch_bounds__(512) void sage_gemm(
    const unsigned short* __restrict__ inA, const unsigned short* __restrict__ inB,
    const unsigned short* __restrict__ Wt, const float* __restrict__ bias,
    unsigned short* __restrict__ outLo, float* __restrict__ outHi)
{
    const int tid  = threadIdx.x;
    const int lane = tid & 63;
    const int wid  = tid >> 6;                 // 0..7
    const int r0   = blockIdx.x * 128 + wid * 16;
    const int lrow = lane & 15;
    const int lk   = lane >> 4;                // 0..3

    int arow = r0 + lrow;
    if (arow >= NN) arow = NN - 1;

    short8 a[4];
    #pragma unroll
    for (int kk = 0; kk < 4; ++kk) {
        int k0 = kk * 32 + lk * 8;
        const unsigned short* ap;
        if (LAYER == 1)
            ap = (k0 < 64) ? (inA + (size_t)arow * 64 + k0)
                           : (inB + (size_t)arow * 64 + (k0 - 64));
        else
            ap = inA + (size_t)arow * 128 + k0;
        a[kk] = *(const short8*)ap;
    }

    f32x4 acc[8];
    #pragma unroll
    for (int c = 0; c < 8; ++c) acc[c] = (f32x4){0.f, 0.f, 0.f, 0.f};

    #pragma unroll
    for (int c = 0; c < 8; ++c) {
        #pragma unroll
        for (int kk = 0; kk < 4; ++kk) {
            short8 b = *(const short8*)(Wt + (size_t)(c * 16 + lrow) * 128 + kk * 32 + lk * 8);
            acc[c] = __builtin_amdgcn_mfma_f32_16x16x32_bf16(a[kk], b, acc[c], 0, 0, 0);
        }
    }

    #pragma unroll
    for (int c = 0; c < 8; ++c) {
        int col = c * 16 + lrow;
        float bv = (LAYER == 1) ? bias[col] : 0.f;
        #pragma unroll
        for (int ri = 0; ri < 4; ++ri) {
            int row = r0 + lk * 4 + ri;
            if (row >= NN) continue;
            float v = acc[c][ri] + bv;
            if (LAYER == 1) {
                v = fmaxf(v, 0.f);
                outLo[(size_t)row * 128 + col] = f2bf(v);
            } else {
                if (col < 64) outLo[(size_t)row * 64 + col] = f2bf(v);
                else          outHi[(size_t)row * 64 + (col - 64)] = v;
            }
        }
    }
}

extern "C" void kernel_launch(void* const* d_in, const int* in_sizes, int n_in,
                              void* d_out, int out_size, void* d_ws, size_t ws_size,
                              hipStream_t stream)
{
    const float* x    = (const float*)d_in[0];
    const int*   ei   = (const int*)d_in[1];
    const float* W1_l = (const float*)d_in[2];
    const float* b1   = (const float*)d_in[3];
    const float* W1_r = (const float*)d_in[4];
    const float* W2_l = (const float*)d_in[5];
    const float* b2   = (const float*)d_in[6];
    const float* W2_r = (const float*)d_in[7];

    float* out = (float*)d_out;
    int*   wi  = (int*)d_ws;

    const int* srcv = ei;
    const int* dstv = ei + NE;

    int* blockHist  = wi + I_BH;
    int* bucketTot  = wi + I_BT;
    int* bucketBase = wi + I_BB;
    int* offs       = wi + I_OFFS;
    int* pairs      = wi + I_PAIRS;
    int* ssrc       = wi + I_SSRC;
    unsigned short* ub  = (unsigned short*)d_ws + U_BASE;
    unsigned short* xb  = ub + U_XB;
    unsigned short* agg = ub + U_AGG;
    unsigned short* h   = ub + U_H;
    unsigned short* p   = ub + U_P;
    unsigned short* Wt1 = ub + U_WT1;
    unsigned short* Wt2 = ub + U_WT2;

    conv_x <<<(NN * 16) / 256, 256, 0, stream>>>(x, xb);
    prep_w <<<64, 256, 0, stream>>>(W1_l, W1_r, W2_l, W2_r, Wt1, Wt2);

    // CSR build: atomic-free two-level multisplit
    p0_hist   <<<NBLK1, 512, 0, stream>>>(dstv, blockHist);
    p_scanA   <<<NBUK, 512, 0, stream>>>(blockHist, bucketTot);
    p_scanB   <<<1, 256, 0, stream>>>(bucketTot, bucketBase, offs);
    p1_scatter<<<NBLK1, 512, 0, stream>>>(srcv, dstv, blockHist, bucketBase, pairs);
    p2_sort   <<<NBUK, 1024, 0, stream>>>(pairs, bucketBase, offs, ssrc);

    // layer 1
    sage_gather<0><<<(NN * 16) / 256, 256, 0, stream>>>(offs, ssrc, xb, nullptr, agg, nullptr);
    sage_gemm<1>  <<<(NN + 127) / 128, 512, 0, stream>>>(agg, xb, Wt1, b1, h, nullptr);

    // layer 2: p (bf16) + q (f32 -> out)
    sage_gemm<2>  <<<(NN + 127) / 128, 512, 0, stream>>>(h, nullptr, Wt2, nullptr, p, out);
    sage_gather<1><<<(NN * 16) / 256, 256, 0, stream>>>(offs, ssrc, p, b2, nullptr, out);
}

// Round 5
// 154.310 us; speedup vs baseline: 15.3049x; 1.3809x over previous
//
#include <hip/hip_runtime.h>

#define NN 100000
#define NE 1250000

#define NBLK1 320      // blocks in pass0/pass1
#define CHUNK 3907     // ceil(NE / NBLK1)
#define NBUK  196      // ceil(NN / 512), bucket = dst >> 9
#define CAP   8192     // pass-2 LDS edge capacity (mean 6378, 26 sigma margin)

typedef __attribute__((ext_vector_type(8))) short short8;
typedef __attribute__((ext_vector_type(4))) float f32x4;

// ---------------- workspace layout ----------------
// int units:
//   blockHist  @ 0       : 62720   [bucket][blk]
//   bucketTot  @ 62720   : 256
//   bucketBase @ 62976   : 256 (needs 197)
//   offs       @ 63232   : 100001 -> pad 163236
//   pairs      @ 163236  : 1250000 -> 1413236
//   ssrc       @ 1413236 : 1250000 -> 2663236
// ushort units (base = 5326472; byte 10,652,944 = 16B aligned):
//   xb  @ 0        : 6,400,000
//   agg @ 6400000  : 6,400,000
//   p   @ 12800000 : 6,400,000
//   Wf1 @ 19200000 : 16384   (frag-order weights)
//   Wf2 @ 19216384 : 16384
static constexpr size_t I_BH    = 0;
static constexpr size_t I_BT    = 62720;
static constexpr size_t I_BB    = 62976;
static constexpr size_t I_OFFS  = 63232;
static constexpr size_t I_PAIRS = 163236;
static constexpr size_t I_SSRC  = 1413236;
static constexpr size_t U_BASE  = 5326472;
static constexpr size_t U_XB    = 0;
static constexpr size_t U_AGG   = 6400000;
static constexpr size_t U_P     = 12800000;
static constexpr size_t U_WF1   = 19200000;
static constexpr size_t U_WF2   = 19216384;

__device__ __forceinline__ float bf2f(unsigned int u16) {
    unsigned int v = u16 << 16;
    return __builtin_bit_cast(float, v);
}
__device__ __forceinline__ unsigned short f2bf(float f) {
    unsigned int u = __builtin_bit_cast(unsigned int, f);
    unsigned int r = (u + 0x7fffu + ((u >> 16) & 1u)) >> 16;
    return (unsigned short)r;
}

// ---------------- x -> bf16 ----------------
__global__ __launch_bounds__(256) void conv_x(const float* __restrict__ x,
                                              unsigned short* __restrict__ xb)
{
    int t = blockIdx.x * 256 + threadIdx.x;
    if (t >= NN * 16) return;
    float4 v = ((const float4*)x)[t];
    *(ushort4*)(xb + (size_t)t * 4) =
        make_ushort4(f2bf(v.x), f2bf(v.y), f2bf(v.z), f2bf(v.w));
}

// ---------------- weight prep: fragment-order bf16 ----------------
// Wf[(c*256 + kk*64 + lk*16 + lrow)*8 + e] = W^T[j=c*16+lrow][k=kk*32+lk*8+e]
__global__ __launch_bounds__(256) void prep_w(
    const float* __restrict__ W1l, const float* __restrict__ W1r,
    const float* __restrict__ W2l, const float* __restrict__ W2r,
    unsigned short* __restrict__ Wf1, unsigned short* __restrict__ Wf2)
{
    int i = blockIdx.x * 256 + threadIdx.x;
    if (i >= 16384) return;
    int e    = i & 7;
    int ch   = i >> 3;
    int lrow = ch & 15;
    int lk   = (ch >> 4) & 3;
    int kk   = (ch >> 6) & 3;
    int c    = ch >> 8;
    int j = c * 16 + lrow;
    int k = kk * 32 + lk * 8 + e;
    float w1 = (k < 64) ? W1l[(size_t)k * 128 + j] : W1r[(size_t)(k - 64) * 128 + j];
    Wf1[i] = f2bf(w1);
    float w2 = (j < 64) ? W2l[(size_t)k * 64 + j] : W2r[(size_t)k * 64 + (j - 64)];
    Wf2[i] = f2bf(w2);
}

// ---------------- pass 0: per-block bucket histogram (LDS only) --------
__global__ __launch_bounds__(512) void p0_hist(const int* __restrict__ dstv,
                                               int* __restrict__ blockHist)
{
    __shared__ int hist[NBUK];
    const int t = threadIdx.x, b = blockIdx.x;
    for (int i = t; i < NBUK; i += 512) hist[i] = 0;
    __syncthreads();
    const int start = b * CHUNK;
    const int end   = min(start + CHUNK, NE);
    for (int e = start + t; e < end; e += 512)
        atomicAdd(&hist[dstv[e] >> 9], 1);
    __syncthreads();
    for (int i = t; i < NBUK; i += 512)
        blockHist[(size_t)i * NBLK1 + b] = hist[i];
}

// ---------------- scan A ----------------
__global__ __launch_bounds__(512) void p_scanA(int* __restrict__ blockHist,
                                               int* __restrict__ bucketTot)
{
    __shared__ int s[512];
    const int b = blockIdx.x, t = threadIdx.x;
    int v = (t < NBLK1) ? blockHist[(size_t)b * NBLK1 + t] : 0;
    s[t] = v;
    __syncthreads();
    for (int d = 1; d < 512; d <<= 1) {
        int x = (t >= d) ? s[t - d] : 0;
        __syncthreads();
        s[t] += x;
        __syncthreads();
    }
    if (t < NBLK1) blockHist[(size_t)b * NBLK1 + t] = s[t] - v;
    if (t == NBLK1 - 1) bucketTot[b] = s[t];
}

// ---------------- scan B ----------------
__global__ __launch_bounds__(256) void p_scanB(const int* __restrict__ bucketTot,
                                               int* __restrict__ bucketBase,
                                               int* __restrict__ offs)
{
    __shared__ int s[256];
    const int t = threadIdx.x;
    int v = (t < NBUK) ? bucketTot[t] : 0;
    s[t] = v;
    __syncthreads();
    for (int d = 1; d < 256; d <<= 1) {
        int x = (t >= d) ? s[t - d] : 0;
        __syncthreads();
        s[t] += x;
        __syncthreads();
    }
    if (t < NBUK) bucketBase[t] = s[t] - v;
    if (t == 0) { bucketBase[NBUK] = NE; offs[NN] = NE; }
}

// ---------------- pass 1: bucket-grouped scatter ----------------
__global__ __launch_bounds__(512) void p1_scatter(
    const int* __restrict__ srcv, const int* __restrict__ dstv,
    const int* __restrict__ blockHist, const int* __restrict__ bucketBase,
    int* __restrict__ pairs)
{
    __shared__ int cur[NBUK];
    const int t = threadIdx.x, b = blockIdx.x;
    for (int i = t; i < NBUK; i += 512)
        cur[i] = bucketBase[i] + blockHist[(size_t)i * NBLK1 + b];
    __syncthreads();
    const int start = b * CHUNK;
    const int end   = min(start + CHUNK, NE);
    for (int e = start + t; e < end; e += 512) {
        int d = dstv[e], s = srcv[e];
        int pos = atomicAdd(&cur[d >> 9], 1);
        pairs[pos] = s | ((d & 511) << 17);
    }
}

// ---------------- pass 2: per-bucket counting sort (LDS) ---------------
__global__ __launch_bounds__(1024) void p2_sort(
    const int* __restrict__ pairs, const int* __restrict__ bucketBase,
    int* __restrict__ offs, int* __restrict__ ssrc)
{
    __shared__ int buf[CAP];
    __shared__ int hist[512];
    const int b = blockIdx.x, t = threadIdx.x;
    const int base = bucketBase[b];
    const int m    = bucketBase[b + 1] - base;
    const bool fits = (m <= CAP);

    if (t < 512) hist[t] = 0;
    __syncthreads();
    for (int i = t; i < m; i += 1024) {
        int v = pairs[base + i];
        if (fits) buf[i] = v;
        atomicAdd(&hist[v >> 17], 1);
    }
    __syncthreads();

    int ov = (t < 512) ? hist[t] : 0;
    __syncthreads();
    for (int d = 1; d < 512; d <<= 1) {
        int x = 0;
        if (t < 512 && t >= d) x = hist[t - d];
        __syncthreads();
        if (t < 512) hist[t] += x;
        __syncthreads();
    }
    int excl = 0;
    if (t < 512) excl = hist[t] - ov;
    __syncthreads();
    if (t < 512) {
        hist[t] = excl;
        int n = b * 512 + t;
        if (n < NN) offs[n] = base + excl;
    }
    __syncthreads();
    for (int i = t; i < m; i += 1024) {
        int v = fits ? buf[i] : pairs[base + i];
        int pos = atomicAdd(&hist[v >> 17], 1);
        ssrc[base + pos] = v & 0x1FFFF;
    }
}

// ---------------- gather-mean: 16 lanes/node = 8 ch x 2 edge-parities --
template <int FUSE>
__global__ __launch_bounds__(256) void sage_gather(
    const int* __restrict__ offs, const int* __restrict__ ssrc,
    const unsigned short* __restrict__ feat,
    const float* __restrict__ b2,
    unsigned short* __restrict__ aggb, float* __restrict__ out)
{
    const int t = blockIdx.x * 256 + threadIdx.x;
    const int n    = t >> 4;
    const int l    = t & 15;
    const int epar = l >> 3;
    const int ch   = l & 7;
    const int e0 = offs[n], e1 = offs[n + 1];

    float acc[8];
    #pragma unroll
    for (int j = 0; j < 8; ++j) acc[j] = 0.f;

    for (int e = e0 + epar; e < e1; e += 2) {
        int s = ssrc[e];
        uint4 u = *(const uint4*)(feat + (size_t)s * 64 + ch * 8);
        acc[0] += bf2f(u.x & 0xffffu); acc[1] += bf2f(u.x >> 16);
        acc[2] += bf2f(u.y & 0xffffu); acc[3] += bf2f(u.y >> 16);
        acc[4] += bf2f(u.z & 0xffffu); acc[5] += bf2f(u.z >> 16);
        acc[6] += bf2f(u.w & 0xffffu); acc[7] += bf2f(u.w >> 16);
    }
    #pragma unroll
    for (int j = 0; j < 8; ++j) acc[j] += __shfl_xor(acc[j], 8);
    if (epar) return;

    const int dg = e1 - e0;
    const float inv = 1.0f / (float)(dg > 0 ? dg : 1);
    #pragma unroll
    for (int j = 0; j < 8; ++j) acc[j] *= inv;

    if (FUSE == 0) {
        uint4 o;
        o.x = (unsigned)f2bf(acc[0]) | ((unsigned)f2bf(acc[1]) << 16);
        o.y = (unsigned)f2bf(acc[2]) | ((unsigned)f2bf(acc[3]) << 16);
        o.z = (unsigned)f2bf(acc[4]) | ((unsigned)f2bf(acc[5]) << 16);
        o.w = (unsigned)f2bf(acc[6]) | ((unsigned)f2bf(acc[7]) << 16);
        *(uint4*)(aggb + (size_t)n * 64 + ch * 8) = o;
    } else {
        float* o = out + (size_t)n * 64 + ch * 8;
        float4 q0 = *(const float4*)(o);
        float4 q1 = *(const float4*)(o + 4);
        float4 c0 = *(const float4*)(b2 + ch * 8);
        float4 c1 = *(const float4*)(b2 + ch * 8 + 4);
        *(float4*)(o)     = make_float4(acc[0] + q0.x + c0.x, acc[1] + q0.y + c0.y,
                                        acc[2] + q0.z + c0.z, acc[3] + q0.w + c0.w);
        *(float4*)(o + 4) = make_float4(acc[4] + q1.x + c1.x, acc[5] + q1.y + c1.y,
                                        acc[6] + q1.z + c1.z, acc[7] + q1.w + c1.w);
    }
}

// ---------------- fused double-GEMM (MFMA, weights in LDS) ----------------
// Per block: 256 threads = 4 waves, each wave owns 16 rows.
//   h = relu([agg|xb] @ W1 + b1)   (kept in per-wave private LDS tile)
//   p = h @ W2_l (bf16) ; q = h @ W2_r (f32 -> out)
// LDS: Wf1 32KB + Wf2 32KB + h 4x4KB = 80KB -> 2 blocks/CU.
__global__ __launch_bounds__(256) void sage_fused(
    const unsigned short* __restrict__ agg, const unsigned short* __restrict__ xb,
    const unsigned short* __restrict__ Wf1, const unsigned short* __restrict__ Wf2,
    const float* __restrict__ b1,
    unsigned short* __restrict__ p, float* __restrict__ outq)
{
    __shared__ __align__(16) unsigned short sW1[16384];
    __shared__ __align__(16) unsigned short sW2[16384];
    __shared__ __align__(16) unsigned short sh[4][2048];

    const int tid  = threadIdx.x;
    const int lane = tid & 63;
    const int wid  = tid >> 6;
    const int lrow = lane & 15;
    const int lk   = lane >> 4;            // 0..3

    // ---- stage weights (linear copy, frag order) ----
    {
        const uint4* g1 = (const uint4*)Wf1;
        const uint4* g2 = (const uint4*)Wf2;
        uint4* s1 = (uint4*)sW1;
        uint4* s2 = (uint4*)sW2;
        #pragma unroll
        for (int i = 0; i < 8; ++i) {
            int idx = tid + i * 256;
            s1[idx] = g1[idx];
            s2[idx] = g2[idx];
        }
    }
    __syncthreads();

    const int rbase = blockIdx.x * 64 + wid * 16;
    int arow = rbase + lrow;
    if (arow >= NN) arow = NN - 1;

    // ---- A1 fragments: [agg | xb] row, k-contiguous 16B ----
    short8 a1[4];
    #pragma unroll
    for (int kk = 0; kk < 4; ++kk) {
        int k0 = kk * 32 + lk * 8;
        const unsigned short* ap = (k0 < 64) ? (agg + (size_t)arow * 64 + k0)
                                             : (xb  + (size_t)arow * 64 + (k0 - 64));
        a1[kk] = *(const short8*)ap;
    }

    const int fragoff = (lk * 16 + lrow) * 8;   // per-lane ushort offset into frag arrays

    // ---- GEMM1 ----
    f32x4 acc1[8];
    #pragma unroll
    for (int c = 0; c < 8; ++c) {
        acc1[c] = (f32x4){0.f, 0.f, 0.f, 0.f};
        #pragma unroll
        for (int kk = 0; kk < 4; ++kk) {
            short8 b = *(const short8*)(sW1 + fragoff + c * 2048 + kk * 512);
            acc1[c] = __builtin_amdgcn_mfma_f32_16x16x32_bf16(a1[kk], b, acc1[c], 0, 0, 0);
        }
    }

    // ---- bias + relu + write h tile (per-wave private, frag-chunk order) ----
    unsigned short* myh = &sh[wid][0];
    #pragma unroll
    for (int c = 0; c < 8; ++c) {
        float bv = b1[c * 16 + lrow];
        int chbase = ((2 * c + (lrow >> 3)) * 16 + lk * 4) * 8 + (lrow & 7);
        #pragma unroll
        for (int ri = 0; ri < 4; ++ri) {
            float v = fmaxf(acc1[c][ri] + bv, 0.f);
            myh[chbase + ri * 8] = f2bf(v);
        }
    }

    // ---- A2 fragments from h tile ----
    short8 a2[4];
    #pragma unroll
    for (int kk = 0; kk < 4; ++kk)
        a2[kk] = *(const short8*)(myh + fragoff + kk * 512);

    // ---- GEMM2 ----
    f32x4 acc2[8];
    #pragma unroll
    for (int c = 0; c < 8; ++c) {
        acc2[c] = (f32x4){0.f, 0.f, 0.f, 0.f};
        #pragma unroll
        for (int kk = 0; kk < 4; ++kk) {
            short8 b = *(const short8*)(sW2 + fragoff + c * 2048 + kk * 512);
            acc2[c] = __builtin_amdgcn_mfma_f32_16x16x32_bf16(a2[kk], b, acc2[c], 0, 0, 0);
        }
    }

    // ---- epilogue: p (bf16, cols 0..63), q -> out (f32, cols 64..127) ----
    #pragma unroll
    for (int c = 0; c < 8; ++c) {
        int col = c * 16 + lrow;
        #pragma unroll
        for (int ri = 0; ri < 4; ++ri) {
            int row = rbase + lk * 4 + ri;
            if (row >= NN) continue;
            if (col < 64) p[(size_t)row * 64 + col] = f2bf(acc2[c][ri]);
            else          outq[(size_t)row * 64 + (col - 64)] = acc2[c][ri];
        }
    }
}

extern "C" void kernel_launch(void* const* d_in, const int* in_sizes, int n_in,
                              void* d_out, int out_size, void* d_ws, size_t ws_size,
                              hipStream_t stream)
{
    const float* x    = (const float*)d_in[0];
    const int*   ei   = (const int*)d_in[1];
    const float* W1_l = (const float*)d_in[2];
    const float* b1   = (const float*)d_in[3];
    const float* W1_r = (const float*)d_in[4];
    const float* W2_l = (const float*)d_in[5];
    const float* b2   = (const float*)d_in[6];
    const float* W2_r = (const float*)d_in[7];

    float* out = (float*)d_out;
    int*   wi  = (int*)d_ws;

    const int* srcv = ei;
    const int* dstv = ei + NE;

    int* blockHist  = wi + I_BH;
    int* bucketTot  = wi + I_BT;
    int* bucketBase = wi + I_BB;
    int* offs       = wi + I_OFFS;
    int* pairs      = wi + I_PAIRS;
    int* ssrc       = wi + I_SSRC;
    unsigned short* ub  = (unsigned short*)d_ws + U_BASE;
    unsigned short* xb  = ub + U_XB;
    unsigned short* agg = ub + U_AGG;
    unsigned short* p   = ub + U_P;
    unsigned short* Wf1 = ub + U_WF1;
    unsigned short* Wf2 = ub + U_WF2;

    conv_x <<<(NN * 16) / 256, 256, 0, stream>>>(x, xb);
    prep_w <<<64, 256, 0, stream>>>(W1_l, W1_r, W2_l, W2_r, Wf1, Wf2);

    // CSR build: atomic-free two-level multisplit
    p0_hist   <<<NBLK1, 512, 0, stream>>>(dstv, blockHist);
    p_scanA   <<<NBUK, 512, 0, stream>>>(blockHist, bucketTot);
    p_scanB   <<<1, 256, 0, stream>>>(bucketTot, bucketBase, offs);
    p1_scatter<<<NBLK1, 512, 0, stream>>>(srcv, dstv, blockHist, bucketBase, pairs);
    p2_sort   <<<NBUK, 1024, 0, stream>>>(pairs, bucketBase, offs, ssrc);

    // layer-1 aggregation
    sage_gather<0><<<(NN * 16) / 256, 256, 0, stream>>>(offs, ssrc, xb, nullptr, agg, nullptr);

    // fused: h = relu([agg|x]@W1+b1);  p = h@W2_l;  q = h@W2_r -> out
    sage_fused<<<(NN + 63) / 64, 256, 0, stream>>>(agg, xb, Wf1, Wf2, b1, p, out);

    // out = mean p over in-neighbors + q + b2
    sage_gather<1><<<(NN * 16) / 256, 256, 0, stream>>>(offs, ssrc, p, b2, nullptr, out);
}